// Round 4
// baseline (385.226 us; speedup 1.0000x reference)
//
#include <hip/hip_runtime.h>

#define H_ 8
#define B_ 2
#define N_ 2048
#define F_ 256
#define O_ 64
#define CAP 256

typedef unsigned short u16;
typedef unsigned int   u32;

__device__ __forceinline__ float us2f(u16 u) {
    union { u32 i; float f; } c; c.i = ((u32)u) << 16; return c.f;
}

// ---------------------------------------------------------------------------
// K-1: marker — fill d_out with 1.0f. Pipeline overwrites all of it; if the
// pipeline kernels fail to run, absmax becomes ~2.203 (vs 3.203 if nothing
// runs at all). Pure diagnostics, negligible cost, same work every call.
// ---------------------------------------------------------------------------
__global__ void marker_kernel(float* __restrict__ out, int n) {
    int i = blockIdx.x * 256 + threadIdx.x;
    if (i < n) out[i] = 1.0f;
}

// ---------------------------------------------------------------------------
// K0: detect input dtype from adj bit patterns.
// fp32 0/1 adjacency words: only 0x00000000 / 0x3F800000.
// bf16 adjacency pairs also produce 0x00003F80 ([1,0]) / 0x3F803F80 ([1,1]):
// ~3000 hits expected in the first 64K words at 5% density. Zero false pos.
// ---------------------------------------------------------------------------
__global__ void detect_kernel(const u32* __restrict__ adj_w, int* __restrict__ flag) {
    __shared__ int found;
    if (threadIdx.x == 0) found = 0;
    __syncthreads();
    for (int i = threadIdx.x; i < 65536; i += 256) {
        u32 w = adj_w[i];
        if (w == 0x00003F80u || w == 0x3F803F80u) found = 1;
    }
    __syncthreads();
    if (threadIdx.x == 0) flag[0] = found;   // 1 = bf16 inputs, 0 = fp32 inputs
}

// ---------------------------------------------------------------------------
// K1: h[h,b,n,o] = sum_f x[b,n,f] * W[h,f,o]   (fp32 accumulate into ws)
// Wave per (h,b,n) row, lane = o; W reads coalesced, x broadcast.
// ---------------------------------------------------------------------------
__global__ void proj_kernel(const void* __restrict__ x,
                            const void* __restrict__ W,
                            const int* __restrict__ flag,
                            float* __restrict__ hbuf) {
    int bf  = flag[0];
    int tid = blockIdx.x * 256 + threadIdx.x;   // 0 .. H*B*N*O-1
    int o  = tid & 63;
    int n  = (tid >> 6) & (N_ - 1);
    int hb = tid >> 17;
    int b  = hb & 1;
    int h  = hb >> 1;

    long xoff = (long)(b * N_ + n) * F_;
    long woff = (long)h * F_ * O_ + o;

    float acc = 0.f;
    if (bf) {
        const u16* xr = (const u16*)x + xoff;
        const u16* Wp = (const u16*)W + woff;
#pragma unroll 8
        for (int f = 0; f < F_; ++f)
            acc = fmaf(us2f(xr[f]), us2f(Wp[(long)f * O_]), acc);
    } else {
        const float* xr = (const float*)x + xoff;
        const float* Wp = (const float*)W + woff;
#pragma unroll 8
        for (int f = 0; f < F_; ++f)
            acc = fmaf(xr[f], Wp[(long)f * O_], acc);
    }
    hbuf[tid] = acc;
}

// ---------------------------------------------------------------------------
// K2: s_src[h,b,n] = h[h,b,n,:]·a_src[h,:]; same for s_dst. Wave per row.
// ---------------------------------------------------------------------------
__global__ void svec_kernel(const float* __restrict__ hbuf,
                            const void* __restrict__ a_src,
                            const void* __restrict__ a_dst,
                            const int* __restrict__ flag,
                            float* __restrict__ ssrc,
                            float* __restrict__ sdst) {
    int bf   = flag[0];
    int wid  = (blockIdx.x * 256 + threadIdx.x) >> 6;  // row = (h*B+b)*N + n
    int lane = threadIdx.x & 63;
    int h    = wid >> 12;                               // B*N = 4096

    float av, dv;
    if (bf) {
        av = us2f(((const u16*)a_src)[h * 64 + lane]);
        dv = us2f(((const u16*)a_dst)[h * 64 + lane]);
    } else {
        av = ((const float*)a_src)[h * 64 + lane];
        dv = ((const float*)a_dst)[h * 64 + lane];
    }
    float hv = hbuf[(size_t)wid * 64 + lane];
    float vs = hv * av;
    float vd = hv * dv;
#pragma unroll
    for (int off = 32; off; off >>= 1) {
        vs += __shfl_down(vs, off);
        vd += __shfl_down(vd, off);
    }
    if (lane == 0) { ssrc[wid] = vs; sdst[wid] = vd; }
}

// ---------------------------------------------------------------------------
// K3: CSR neighbor list per (b,i) row (shared across heads).
// ---------------------------------------------------------------------------
__global__ void csr_kernel(const void* __restrict__ adj,
                           const int* __restrict__ flag,
                           int* __restrict__ cnt,
                           u16* __restrict__ nidx) {
    __shared__ int scnt;
    __shared__ u16 sidx[CAP];
    int row = blockIdx.x;
    if (threadIdx.x == 0) scnt = 0;
    __syncthreads();

    if (flag[0]) {
        const u16* arow = (const u16*)adj + (size_t)row * N_;
        for (int j = threadIdx.x; j < N_; j += 256) {
            if (arow[j] != 0) {
                int p = atomicAdd(&scnt, 1);
                if (p < CAP) sidx[p] = (u16)j;
            }
        }
    } else {
        const float* arow = (const float*)adj + (size_t)row * N_;
        for (int j = threadIdx.x; j < N_; j += 256) {
            if (arow[j] > 0.f) {
                int p = atomicAdd(&scnt, 1);
                if (p < CAP) sidx[p] = (u16)j;
            }
        }
    }
    __syncthreads();
    int m = scnt < CAP ? scnt : CAP;
    if (threadIdx.x == 0) cnt[row] = m;
    for (int k = threadIdx.x; k < m; k += 256) nidx[(size_t)row * CAP + k] = sidx[k];
}

// ---------------------------------------------------------------------------
// K4: per (h,b,i): masked softmax over neighbors + aggregation. FP32 stores.
// ---------------------------------------------------------------------------
__global__ void GATLayer_88072599371930_kernel(const float* __restrict__ hbuf,
                                               const float* __restrict__ ssrc,
                                               const float* __restrict__ sdst,
                                               const int* __restrict__ cnt,
                                               const u16* __restrict__ nidx,
                                               float* __restrict__ out) {
    __shared__ float se[CAP];
    __shared__ int   sj[CAP];
    __shared__ float red[8];
    __shared__ float sbr[2];
    __shared__ float sacc[256];

    int blk = blockIdx.x;
    int h   = blk >> 12;          // B*N = 4096 blocks per head
    int bi  = blk & 4095;         // b*N + i
    int tid = threadIdx.x;
    int n   = cnt[bi];
    const u16* nb = nidx + (size_t)bi * CAP;
    int srow = (h * B_ + (bi >> 11)) * N_;   // row base into [H,B,N] arrays

    if (n <= 0) {   // sentinel: adjacency parse produced nothing (diagnostic)
        if (tid < 64)
            out[(size_t)bi * (H_ * O_) + h * O_ + tid] = 999.0f;
        return;
    }

    // Phase 1: scores + block max
    float sd = sdst[srow + (bi & (N_ - 1))];
    float lmax = -3.4e38f;
    for (int k = tid; k < n; k += 256) {
        int j = nb[k];
        float v = sd + ssrc[srow + j];
        v = v > 0.f ? v : 0.2f * v;     // leaky_relu(0.2)
        se[k] = v;
        sj[k] = j;
        lmax = fmaxf(lmax, v);
    }
#pragma unroll
    for (int off = 32; off; off >>= 1) lmax = fmaxf(lmax, __shfl_down(lmax, off));
    if ((tid & 63) == 0) red[tid >> 6] = lmax;
    __syncthreads();
    if (tid == 0) sbr[0] = fmaxf(fmaxf(red[0], red[1]), fmaxf(red[2], red[3]));
    __syncthreads();
    float m = sbr[0];

    // Phase 2: exp + block sum
    float lsum = 0.f;
    for (int k = tid; k < n; k += 256) {
        float e = __expf(se[k] - m);
        se[k] = e;
        lsum += e;
    }
#pragma unroll
    for (int off = 32; off; off >>= 1) lsum += __shfl_down(lsum, off);
    if ((tid & 63) == 0) red[4 + (tid >> 6)] = lsum;
    __syncthreads();
    if (tid == 0) sbr[1] = (red[4] + red[5]) + (red[6] + red[7]);
    __syncthreads();
    float Z  = sbr[1];
    float rZ = (Z > 0.f) ? 1.f / Z : 0.f;

    // Phase 3: out[o] = relu( (1/Z) * sum_k e_k * h[j_k, o] )
    int o  = tid & 63;
    int jj = tid >> 6;
    const float* hb_base = hbuf + (size_t)srow * 64;
    float acc = 0.f;
    for (int k = jj; k < n; k += 4)
        acc = fmaf(se[k], hb_base[(size_t)sj[k] * 64 + o], acc);
    sacc[tid] = acc;
    __syncthreads();
    if (tid < 64) {
        float t = (sacc[tid] + sacc[tid + 64]) + (sacc[tid + 128] + sacc[tid + 192]);
        t *= rZ;
        t = t > 0.f ? t : 0.f;
        out[(size_t)bi * (H_ * O_) + h * O_ + o] = t;   // FP32 store
    }
}

// ---------------------------------------------------------------------------
extern "C" void kernel_launch(void* const* d_in, const int* in_sizes, int n_in,
                              void* d_out, int out_size, void* d_ws, size_t ws_size,
                              hipStream_t stream) {
    const void *x = 0, *adj = 0, *W = 0, *a_src = 0, *a_dst = 0;
    for (int i = 0; i < n_in; ++i) {
        long sz = in_sizes[i];
        if (sz == (long)B_ * N_ * F_)      x = d_in[i];
        else if (sz == (long)B_ * N_ * N_) adj = d_in[i];
        else if (sz == (long)H_ * F_ * O_) W = d_in[i];
        else if (sz == (long)H_ * O_) { if (!a_src) a_src = d_in[i]; else a_dst = d_in[i]; }
    }
    if (!x)     x     = d_in[0];
    if (!adj)   adj   = d_in[1];
    if (!W)     W     = d_in[2];
    if (!a_src) a_src = d_in[3];
    if (!a_dst) a_dst = d_in[4];

    float* out = (float*)d_out;

    char* ws = (char*)d_ws;
    size_t off = 0;
    int*   flag = (int*)(ws + off);   off += 256;
    float* hbuf = (float*)(ws + off); off += (size_t)H_ * B_ * N_ * O_ * 4;  // 8 MB
    float* ssrc = (float*)(ws + off); off += (size_t)H_ * B_ * N_ * 4;       // 128 KB
    float* sdst = (float*)(ws + off); off += (size_t)H_ * B_ * N_ * 4;       // 128 KB
    int*   cnt  = (int*)(ws + off);   off += (size_t)B_ * N_ * 4;            // 16 KB
    u16*   nidx = (u16*)(ws + off);   off += (size_t)B_ * N_ * CAP * 2;      // 2 MB

    marker_kernel<<<dim3((out_size + 255) / 256), dim3(256), 0, stream>>>(out, out_size);
    detect_kernel<<<dim3(1), dim3(256), 0, stream>>>((const u32*)adj, flag);

    proj_kernel<<<dim3(H_ * B_ * N_ * O_ / 256), dim3(256), 0, stream>>>(x, W, flag, hbuf);
    csr_kernel<<<dim3(B_ * N_), dim3(256), 0, stream>>>(adj, flag, cnt, nidx);
    svec_kernel<<<dim3(H_ * B_ * N_ / 4), dim3(256), 0, stream>>>(hbuf, a_src, a_dst, flag, ssrc, sdst);
    GATLayer_88072599371930_kernel<<<dim3(H_ * B_ * N_), dim3(256), 0, stream>>>(
        hbuf, ssrc, sdst, cnt, nidx, out);
}

// Round 5
// 289.636 us; speedup vs baseline: 1.3300x; 1.3300x over previous
//
#include <hip/hip_runtime.h>

#define H_ 8
#define B_ 2
#define N_ 2048
#define F_ 256
#define O_ 64
#define CAP 256

typedef unsigned short u16;
typedef unsigned int   u32;

__device__ __forceinline__ float us2f(u16 u) {
    union { u32 i; float f; } c; c.i = ((u32)u) << 16; return c.f;
}

// ---------------------------------------------------------------------------
// K0: detect input dtype from adj bit patterns (bf16 vs fp32).
// fp32 0/1 adjacency words: only 0x00000000 / 0x3F800000.
// bf16 pairs also produce 0x00003F80 ([1,0]) / 0x3F803F80 ([1,1]).
// ---------------------------------------------------------------------------
__global__ void detect_kernel(const u32* __restrict__ adj_w, int* __restrict__ flag) {
    __shared__ int found;
    if (threadIdx.x == 0) found = 0;
    __syncthreads();
    for (int i = threadIdx.x; i < 65536; i += 256) {
        u32 w = adj_w[i];
        if (w == 0x00003F80u || w == 0x3F803F80u) found = 1;
    }
    __syncthreads();
    if (threadIdx.x == 0) flag[0] = found;   // 1 = bf16 inputs, 0 = fp32
}

// ---------------------------------------------------------------------------
// K1: projection + fused attention-vector dots.
//   hT[b][n][h][o] = sum_f x[b,n,f] * W[h,f,o]        (fp32, transposed!)
//   sTsrc[b][n][h] = hT[b,n,h,:] . a_src[h,:]
//   sTdst[b][n][h] = hT[b,n,h,:] . a_dst[h,:]
// One wave per (h,b,n); lane = o. W reads coalesced 128B/f, x broadcast.
// ---------------------------------------------------------------------------
__global__ void proj_kernel(const void* __restrict__ x,
                            const void* __restrict__ W,
                            const void* __restrict__ a_src,
                            const void* __restrict__ a_dst,
                            const int* __restrict__ flag,
                            float* __restrict__ hT,
                            float* __restrict__ sTsrc,
                            float* __restrict__ sTdst) {
    int bf   = flag[0];
    int gt   = blockIdx.x * 256 + threadIdx.x;
    int o    = gt & 63;
    int wid  = gt >> 6;             // 0 .. H*B*N-1
    int h    = wid >> 12;           // B*N = 4096 per head
    int bn   = wid & 4095;          // b*N + n

    long xoff = (long)bn * F_;
    long woff = (long)h * F_ * O_ + o;

    float acc = 0.f;
    if (bf) {
        const u16* xr = (const u16*)x + xoff;
        const u16* Wp = (const u16*)W + woff;
#pragma unroll 8
        for (int f = 0; f < F_; ++f)
            acc = fmaf(us2f(xr[f]), us2f(Wp[(long)f * O_]), acc);
    } else {
        const float* xr = (const float*)x + xoff;
        const float* Wp = (const float*)W + woff;
#pragma unroll 8
        for (int f = 0; f < F_; ++f)
            acc = fmaf(xr[f], Wp[(long)f * O_], acc);
    }
    hT[(size_t)bn * (H_ * O_) + h * O_ + o] = acc;

    float av, dv;
    if (bf) {
        av = us2f(((const u16*)a_src)[h * 64 + o]);
        dv = us2f(((const u16*)a_dst)[h * 64 + o]);
    } else {
        av = ((const float*)a_src)[h * 64 + o];
        dv = ((const float*)a_dst)[h * 64 + o];
    }
    float vs = acc * av;
    float vd = acc * dv;
#pragma unroll
    for (int off = 32; off; off >>= 1) {
        vs += __shfl_down(vs, off);
        vd += __shfl_down(vd, off);
    }
    if (o == 0) {
        sTsrc[(size_t)bn * H_ + h] = vs;
        sTdst[(size_t)bn * H_ + h] = vd;
    }
}

// ---------------------------------------------------------------------------
// K2: CSR neighbor list per (b,i) row (shared across heads).
// ---------------------------------------------------------------------------
__global__ void csr_kernel(const void* __restrict__ adj,
                           const int* __restrict__ flag,
                           int* __restrict__ cnt,
                           u16* __restrict__ nidx) {
    __shared__ int scnt;
    __shared__ u16 sidx[CAP];
    int row = blockIdx.x;
    if (threadIdx.x == 0) scnt = 0;
    __syncthreads();

    if (flag[0]) {
        const u16* arow = (const u16*)adj + (size_t)row * N_;
        for (int j = threadIdx.x; j < N_; j += 256) {
            if (arow[j] != 0) {
                int p = atomicAdd(&scnt, 1);
                if (p < CAP) sidx[p] = (u16)j;
            }
        }
    } else {
        const float* arow = (const float*)adj + (size_t)row * N_;
        for (int j = threadIdx.x; j < N_; j += 256) {
            if (arow[j] > 0.f) {
                int p = atomicAdd(&scnt, 1);
                if (p < CAP) sidx[p] = (u16)j;
            }
        }
    }
    __syncthreads();
    int m = scnt < CAP ? scnt : CAP;
    if (threadIdx.x == 0) cnt[row] = m;
    for (int k = threadIdx.x; k < m; k += 256) nidx[(size_t)row * CAP + k] = sidx[k];
}

// ---------------------------------------------------------------------------
// K3: one block per (b,i), ALL 8 heads. Masked softmax + aggregation.
// Phase1: raw scores (all threads, coalesced 32B score gathers) -> LDS [k][h].
// Phase2: wave0 per-head max; all-thread exp; wave0 per-head sum.
// Phase3: float4 gathers of hT rows (2KB contiguous per neighbor),
//         thread t = (slot=t>>7, h=(t>>4)&7, oq=t&15), k += 2 per slot.
// ---------------------------------------------------------------------------
__global__ void GATLayer_88072599371930_kernel(const float* __restrict__ hT,
                                               const float* __restrict__ sTsrc,
                                               const float* __restrict__ sTdst,
                                               const int* __restrict__ cnt,
                                               const u16* __restrict__ nidx,
                                               float* __restrict__ out) {
    __shared__ u16   sj[CAP];
    __shared__ float se[CAP * H_];     // [k][h], 8 KB
    __shared__ float mh[H_];
    __shared__ float rzh[H_];
    __shared__ float sdl[H_];
    __shared__ float sred[128 * 4];    // slot-1 partial float4s

    int bi  = blockIdx.x;              // b*N + i
    int tid = threadIdx.x;
    int n   = cnt[bi];
    int base = bi & ~(N_ - 1);         // b*N  (N power of 2)

    if (tid < 8) sdl[tid] = sTdst[(size_t)bi * H_ + tid];
    if (tid < n) sj[tid] = nidx[(size_t)bi * CAP + tid];
    __syncthreads();

    if (n <= 0) {                       // can't happen (self-loops); diagnostic
        out[(size_t)bi * 512 + tid] = 999.0f;
        out[(size_t)bi * 512 + 256 + tid] = 999.0f;
        return;
    }

    // Phase 1: raw leaky-relu scores, [k][h] layout
    int tot = n * H_;
    for (int idx = tid; idx < tot; idx += 256) {
        int k  = idx >> 3;
        int hh = idx & 7;
        int j  = sj[k];
        float v = sdl[hh] + sTsrc[(size_t)(base + j) * H_ + hh];
        v = v > 0.f ? v : 0.2f * v;
        se[idx] = v;
    }
    __syncthreads();

    // Phase 2a: per-head max (wave 0; lane = hh*8 + kk)
    if (tid < 64) {
        int hh = tid >> 3, kk = tid & 7;
        float lm = -3.4e38f;
        for (int k = kk; k < n; k += 8) lm = fmaxf(lm, se[k * 8 + hh]);
#pragma unroll
        for (int mm = 1; mm < 8; mm <<= 1) lm = fmaxf(lm, __shfl_xor(lm, mm));
        if (kk == 0) mh[hh] = lm;
    }
    __syncthreads();

    // Phase 2b: exp (all threads)
    for (int idx = tid; idx < tot; idx += 256) {
        int hh = idx & 7;
        se[idx] = __expf(se[idx] - mh[hh]);
    }
    __syncthreads();

    // Phase 2c: per-head sum -> 1/Z (wave 0)
    if (tid < 64) {
        int hh = tid >> 3, kk = tid & 7;
        float ls = 0.f;
        for (int k = kk; k < n; k += 8) ls += se[k * 8 + hh];
#pragma unroll
        for (int mm = 1; mm < 8; mm <<= 1) ls += __shfl_xor(ls, mm);
        if (kk == 0) rzh[hh] = 1.f / ls;
    }
    __syncthreads();

    // Phase 3: aggregation. slot handles k = slot, slot+2, ...
    int slot = tid >> 7;
    int hh   = (tid >> 4) & 7;
    int oq   = tid & 15;
    const float* hb = hT + (size_t)base * 512;
    float a0 = 0.f, a1 = 0.f, a2 = 0.f, a3 = 0.f;
    for (int k = slot; k < n; k += 2) {
        int j   = sj[k];
        float w = se[k * 8 + hh];
        const float4 hv = *(const float4*)(hb + (size_t)j * 512 + hh * 64 + oq * 4);
        a0 = fmaf(w, hv.x, a0);
        a1 = fmaf(w, hv.y, a1);
        a2 = fmaf(w, hv.z, a2);
        a3 = fmaf(w, hv.w, a3);
    }
    if (slot == 1) {
        float4 t; t.x = a0; t.y = a1; t.z = a2; t.w = a3;
        ((float4*)sred)[tid - 128] = t;
    }
    __syncthreads();
    if (slot == 0) {
        float4 p = ((float4*)sred)[tid];
        float rz = rzh[hh];
        float4 r;
        r.x = fmaxf((a0 + p.x) * rz, 0.f);
        r.y = fmaxf((a1 + p.y) * rz, 0.f);
        r.z = fmaxf((a2 + p.z) * rz, 0.f);
        r.w = fmaxf((a3 + p.w) * rz, 0.f);
        *(float4*)(out + (size_t)bi * 512 + tid * 4) = r;   // [bi][h][o], coalesced
    }
}

// ---------------------------------------------------------------------------
extern "C" void kernel_launch(void* const* d_in, const int* in_sizes, int n_in,
                              void* d_out, int out_size, void* d_ws, size_t ws_size,
                              hipStream_t stream) {
    const void *x = 0, *adj = 0, *W = 0, *a_src = 0, *a_dst = 0;
    for (int i = 0; i < n_in; ++i) {
        long sz = in_sizes[i];
        if (sz == (long)B_ * N_ * F_)      x = d_in[i];
        else if (sz == (long)B_ * N_ * N_) adj = d_in[i];
        else if (sz == (long)H_ * F_ * O_) W = d_in[i];
        else if (sz == (long)H_ * O_) { if (!a_src) a_src = d_in[i]; else a_dst = d_in[i]; }
    }
    if (!x)     x     = d_in[0];
    if (!adj)   adj   = d_in[1];
    if (!W)     W     = d_in[2];
    if (!a_src) a_src = d_in[3];
    if (!a_dst) a_dst = d_in[4];

    float* out = (float*)d_out;

    char* ws = (char*)d_ws;
    size_t off = 0;
    int*   flag  = (int*)(ws + off);   off += 256;
    float* hT    = (float*)(ws + off); off += (size_t)B_ * N_ * H_ * O_ * 4;  // 8 MB
    float* sTsrc = (float*)(ws + off); off += (size_t)B_ * N_ * H_ * 4;       // 128 KB
    float* sTdst = (float*)(ws + off); off += (size_t)B_ * N_ * H_ * 4;       // 128 KB
    int*   cnt   = (int*)(ws + off);   off += (size_t)B_ * N_ * 4;            // 16 KB
    u16*   nidx  = (u16*)(ws + off);   off += (size_t)B_ * N_ * CAP * 2;      // 2 MB

    detect_kernel<<<dim3(1), dim3(256), 0, stream>>>((const u32*)adj, flag);
    proj_kernel<<<dim3(H_ * B_ * N_ / 4), dim3(256), 0, stream>>>(
        x, W, a_src, a_dst, flag, hT, sTsrc, sTdst);
    csr_kernel<<<dim3(B_ * N_), dim3(256), 0, stream>>>(adj, flag, cnt, nidx);
    GATLayer_88072599371930_kernel<<<dim3(B_ * N_), dim3(256), 0, stream>>>(
        hT, sTsrc, sTdst, cnt, nidx, out);
}

// Round 6
// 150.485 us; speedup vs baseline: 2.5599x; 1.9247x over previous
//
#include <hip/hip_runtime.h>

#define H_ 8
#define B_ 2
#define N_ 2048
#define F_ 256
#define O_ 64
#define CAP 256
#define KPAD 264   // 256 + 8 bf16 pad -> row stride 528 B (16B-aligned, 2-way banks)

typedef unsigned short u16;
typedef unsigned int   u32;
typedef __attribute__((ext_vector_type(8))) short bf16x8;
typedef __attribute__((ext_vector_type(4))) float f32x4;

__device__ __forceinline__ float us2f(u16 u) {
    union { u32 i; float f; } c; c.i = ((u32)u) << 16; return c.f;
}
__device__ __forceinline__ u16 f2us(float f) {
    union { float f; u32 i; } c; c.f = f; return (u16)(c.i >> 16);  // truncate (fallback path only)
}

// ---------------------------------------------------------------------------
// K0: detect input dtype from adj bit patterns (bf16 vs fp32).
// fp32 0/1 adjacency words: only 0x00000000 / 0x3F800000.
// bf16 pairs also produce 0x00003F80 ([1,0]) / 0x3F803F80 ([1,1]).
// ---------------------------------------------------------------------------
__global__ void detect_kernel(const uint4* __restrict__ adj_v, int* __restrict__ flag) {
    __shared__ int found;
    if (threadIdx.x == 0) found = 0;
    __syncthreads();
#pragma unroll
    for (int i = 0; i < 16; ++i) {
        uint4 v = adj_v[threadIdx.x * 16 + i];
        u32 w[4] = {v.x, v.y, v.z, v.w};
        for (int q = 0; q < 4; ++q)
            if (w[q] == 0x00003F80u || w[q] == 0x3F803F80u) found = 1;
    }
    __syncthreads();
    if (threadIdx.x == 0) flag[0] = found;   // 1 = bf16 inputs, 0 = fp32
}

// ---------------------------------------------------------------------------
// K1: MFMA projection + fused attention-vector dots.
// Block = 64 bn-rows x 1 head. LDS: x-tile [64][KPAD], W^T [64][KPAD] (bf16).
// Wave w computes rows 16w..16w+15, all 64 o (4 n-tiles), K=256 in 8 steps.
//   hT[bn][h][o]  (fp32),  sTsrc/sTdst[bn][h]
// ---------------------------------------------------------------------------
__global__ __launch_bounds__(256) void proj_kernel(const void* __restrict__ x,
                                                   const void* __restrict__ W,
                                                   const void* __restrict__ a_src,
                                                   const void* __restrict__ a_dst,
                                                   const int* __restrict__ flag,
                                                   float* __restrict__ hT,
                                                   float* __restrict__ sTsrc,
                                                   float* __restrict__ sTdst) {
    __shared__ alignas(16) u16 xs[64 * KPAD];
    __shared__ alignas(16) u16 wt[64 * KPAD];

    int bf   = flag[0];
    int bx   = blockIdx.x;
    int h    = bx & 7;
    int bn0  = (bx >> 3) * 64;
    int tid  = threadIdx.x;
    int wave = tid >> 6;
    int lane = tid & 63;

    // --- stage x tile (rows bn0..bn0+63) ---
    if (bf) {
        const u16* xg = (const u16*)x;
#pragma unroll
        for (int p = 0; p < 8; ++p) {
            int r = wave * 16 + p * 2 + (lane >> 5);
            int c = (lane & 31) * 8;
            *(uint4*)(xs + r * KPAD + c) = *(const uint4*)(xg + (size_t)(bn0 + r) * F_ + c);
        }
    } else {
        const float* xg = (const float*)x;
#pragma unroll
        for (int p = 0; p < 8; ++p) {
            int r = wave * 16 + p * 2 + (lane >> 5);
            int c = (lane & 31) * 8;
            for (int q = 0; q < 8; ++q)
                xs[r * KPAD + c + q] = f2us(xg[(size_t)(bn0 + r) * F_ + c + q]);
        }
    }
    // --- stage W^T for head h: wt[o][f] = W[h][f][o] ---
    {
        int o  = tid & 63;
        int fq = tid >> 6;                 // 0..3
        if (bf) {
            const u16* wg = (const u16*)W + (size_t)h * F_ * O_;
            for (int i = 0; i < 64; ++i) {
                int f = fq * 64 + i;
                wt[o * KPAD + f] = wg[(size_t)f * O_ + o];
            }
        } else {
            const float* wg = (const float*)W + (size_t)h * F_ * O_;
            for (int i = 0; i < 64; ++i) {
                int f = fq * 64 + i;
                wt[o * KPAD + f] = f2us(wg[(size_t)f * O_ + o]);
            }
        }
    }
    __syncthreads();

    int m_l  = lane & 15;
    int quad = lane >> 4;
    int mrow = wave * 16 + m_l;

    f32x4 acc[4] = {{0,0,0,0},{0,0,0,0},{0,0,0,0},{0,0,0,0}};
#pragma unroll
    for (int ks = 0; ks < 8; ++ks) {
        int kofs = ks * 32 + quad * 8;
        bf16x8 afrag = *(const bf16x8*)(xs + mrow * KPAD + kofs);
#pragma unroll
        for (int nt = 0; nt < 4; ++nt) {
            bf16x8 bfrag = *(const bf16x8*)(wt + (nt * 16 + m_l) * KPAD + kofs);
            acc[nt] = __builtin_amdgcn_mfma_f32_16x16x32_bf16(afrag, bfrag, acc[nt], 0, 0, 0);
        }
    }

    // --- epilogue: store hT + fused a_src/a_dst row dots ---
    float asv[4], adv[4];
#pragma unroll
    for (int nt = 0; nt < 4; ++nt) {
        int o = nt * 16 + m_l;
        if (bf) {
            asv[nt] = us2f(((const u16*)a_src)[h * 64 + o]);
            adv[nt] = us2f(((const u16*)a_dst)[h * 64 + o]);
        } else {
            asv[nt] = ((const float*)a_src)[h * 64 + o];
            adv[nt] = ((const float*)a_dst)[h * 64 + o];
        }
    }
    float vs[4] = {0,0,0,0}, vd[4] = {0,0,0,0};
#pragma unroll
    for (int nt = 0; nt < 4; ++nt)
#pragma unroll
        for (int r = 0; r < 4; ++r) {
            float hv = acc[nt][r];
            int row = wave * 16 + quad * 4 + r;   // C/D: row = quad*4+reg, col = lane&15
            hT[(size_t)(bn0 + row) * (H_ * O_) + h * O_ + nt * 16 + m_l] = hv;
            vs[r] = fmaf(hv, asv[nt], vs[r]);
            vd[r] = fmaf(hv, adv[nt], vd[r]);
        }
#pragma unroll
    for (int r = 0; r < 4; ++r)
#pragma unroll
        for (int off = 1; off < 16; off <<= 1) {
            vs[r] += __shfl_xor(vs[r], off);
            vd[r] += __shfl_xor(vd[r], off);
        }
    if (m_l == 0) {
#pragma unroll
        for (int r = 0; r < 4; ++r) {
            int row = wave * 16 + quad * 4 + r;
            sTsrc[(size_t)(bn0 + row) * H_ + h] = vs[r];
            sTdst[(size_t)(bn0 + row) * H_ + h] = vd[r];
        }
    }
}

// ---------------------------------------------------------------------------
// K2: CSR neighbor list per (b,i) row (shared across heads). uint4 loads.
// ---------------------------------------------------------------------------
__global__ void csr_kernel(const void* __restrict__ adj,
                           const int* __restrict__ flag,
                           int* __restrict__ cnt,
                           u16* __restrict__ nidx) {
    __shared__ int scnt;
    __shared__ u16 sidx[CAP];
    int row = blockIdx.x;
    int tid = threadIdx.x;
    if (tid == 0) scnt = 0;
    __syncthreads();

    if (flag[0]) {
        const u16* arow = (const u16*)adj + (size_t)row * N_;
        uint4 v = *(const uint4*)(arow + tid * 8);
        u32 w[4] = {v.x, v.y, v.z, v.w};
        int j0 = tid * 8;
#pragma unroll
        for (int q = 0; q < 4; ++q) {
            if (w[q] & 0xFFFFu) { int p = atomicAdd(&scnt, 1); if (p < CAP) sidx[p] = (u16)(j0 + 2 * q); }
            if (w[q] >> 16)     { int p = atomicAdd(&scnt, 1); if (p < CAP) sidx[p] = (u16)(j0 + 2 * q + 1); }
        }
    } else {
        const float* arow = (const float*)adj + (size_t)row * N_;
        for (int j = tid; j < N_; j += 256) {
            if (arow[j] > 0.f) { int p = atomicAdd(&scnt, 1); if (p < CAP) sidx[p] = (u16)j; }
        }
    }
    __syncthreads();
    int m = scnt < CAP ? scnt : CAP;
    if (tid == 0) cnt[row] = m;
    for (int k = tid; k < m; k += 256) nidx[(size_t)row * CAP + k] = sidx[k];
}

// ---------------------------------------------------------------------------
// K3: one block per (b,i), ALL 8 heads. Masked softmax + aggregation.
// ---------------------------------------------------------------------------
__global__ void GATLayer_88072599371930_kernel(const float* __restrict__ hT,
                                               const float* __restrict__ sTsrc,
                                               const float* __restrict__ sTdst,
                                               const int* __restrict__ cnt,
                                               const u16* __restrict__ nidx,
                                               float* __restrict__ out) {
    __shared__ u16   sj[CAP];
    __shared__ float se[CAP * H_];     // [k][h]
    __shared__ float mh[H_];
    __shared__ float rzh[H_];
    __shared__ float sdl[H_];
    __shared__ float sred[128 * 4];

    int bi  = blockIdx.x;
    int tid = threadIdx.x;
    int n   = cnt[bi];
    int base = bi & ~(N_ - 1);

    if (tid < 8) sdl[tid] = sTdst[(size_t)bi * H_ + tid];
    if (tid < n) sj[tid] = nidx[(size_t)bi * CAP + tid];
    __syncthreads();

    if (n <= 0) {
        out[(size_t)bi * 512 + tid] = 999.0f;
        out[(size_t)bi * 512 + 256 + tid] = 999.0f;
        return;
    }

    int tot = n * H_;
    for (int idx = tid; idx < tot; idx += 256) {
        int k  = idx >> 3;
        int hh = idx & 7;
        int j  = sj[k];
        float v = sdl[hh] + sTsrc[(size_t)(base + j) * H_ + hh];
        v = v > 0.f ? v : 0.2f * v;
        se[idx] = v;
    }
    __syncthreads();

    if (tid < 64) {
        int hh = tid >> 3, kk = tid & 7;
        float lm = -3.4e38f;
        for (int k = kk; k < n; k += 8) lm = fmaxf(lm, se[k * 8 + hh]);
#pragma unroll
        for (int mm = 1; mm < 8; mm <<= 1) lm = fmaxf(lm, __shfl_xor(lm, mm));
        if (kk == 0) mh[hh] = lm;
    }
    __syncthreads();

    for (int idx = tid; idx < tot; idx += 256) {
        int hh = idx & 7;
        se[idx] = __expf(se[idx] - mh[hh]);
    }
    __syncthreads();

    if (tid < 64) {
        int hh = tid >> 3, kk = tid & 7;
        float ls = 0.f;
        for (int k = kk; k < n; k += 8) ls += se[k * 8 + hh];
#pragma unroll
        for (int mm = 1; mm < 8; mm <<= 1) ls += __shfl_xor(ls, mm);
        if (kk == 0) rzh[hh] = 1.f / ls;
    }
    __syncthreads();

    int slot = tid >> 7;
    int hh   = (tid >> 4) & 7;
    int oq   = tid & 15;
    const float* hb = hT + (size_t)base * 512;
    float a0 = 0.f, a1 = 0.f, a2 = 0.f, a3 = 0.f;
    for (int k = slot; k < n; k += 2) {
        int j   = sj[k];
        float w = se[k * 8 + hh];
        const float4 hv = *(const float4*)(hb + (size_t)j * 512 + hh * 64 + oq * 4);
        a0 = fmaf(w, hv.x, a0);
        a1 = fmaf(w, hv.y, a1);
        a2 = fmaf(w, hv.z, a2);
        a3 = fmaf(w, hv.w, a3);
    }
    if (slot == 1) {
        float4 t; t.x = a0; t.y = a1; t.z = a2; t.w = a3;
        ((float4*)sred)[tid - 128] = t;
    }
    __syncthreads();
    if (slot == 0) {
        float4 p = ((float4*)sred)[tid];
        float rz = rzh[hh];
        float4 r;
        r.x = fmaxf((a0 + p.x) * rz, 0.f);
        r.y = fmaxf((a1 + p.y) * rz, 0.f);
        r.z = fmaxf((a2 + p.z) * rz, 0.f);
        r.w = fmaxf((a3 + p.w) * rz, 0.f);
        *(float4*)(out + (size_t)bi * 512 + tid * 4) = r;
    }
}

// ---------------------------------------------------------------------------
extern "C" void kernel_launch(void* const* d_in, const int* in_sizes, int n_in,
                              void* d_out, int out_size, void* d_ws, size_t ws_size,
                              hipStream_t stream) {
    const void *x = 0, *adj = 0, *W = 0, *a_src = 0, *a_dst = 0;
    for (int i = 0; i < n_in; ++i) {
        long sz = in_sizes[i];
        if (sz == (long)B_ * N_ * F_)      x = d_in[i];
        else if (sz == (long)B_ * N_ * N_) adj = d_in[i];
        else if (sz == (long)H_ * F_ * O_) W = d_in[i];
        else if (sz == (long)H_ * O_) { if (!a_src) a_src = d_in[i]; else a_dst = d_in[i]; }
    }
    if (!x)     x     = d_in[0];
    if (!adj)   adj   = d_in[1];
    if (!W)     W     = d_in[2];
    if (!a_src) a_src = d_in[3];
    if (!a_dst) a_dst = d_in[4];

    float* out = (float*)d_out;

    char* ws = (char*)d_ws;
    size_t off = 0;
    int*   flag  = (int*)(ws + off);   off += 256;
    float* hT    = (float*)(ws + off); off += (size_t)B_ * N_ * H_ * O_ * 4;  // 8 MB
    float* sTsrc = (float*)(ws + off); off += (size_t)B_ * N_ * H_ * 4;       // 128 KB
    float* sTdst = (float*)(ws + off); off += (size_t)B_ * N_ * H_ * 4;       // 128 KB
    int*   cnt   = (int*)(ws + off);   off += (size_t)B_ * N_ * 4;            // 16 KB
    u16*   nidx  = (u16*)(ws + off);   off += (size_t)B_ * N_ * CAP * 2;      // 2 MB

    detect_kernel<<<dim3(1), dim3(256), 0, stream>>>((const uint4*)adj, flag);
    proj_kernel<<<dim3((N_ * B_ / 64) * H_), dim3(256), 0, stream>>>(
        x, W, a_src, a_dst, flag, hT, sTsrc, sTdst);
    csr_kernel<<<dim3(B_ * N_), dim3(256), 0, stream>>>(adj, flag, cnt, nidx);
    GATLayer_88072599371930_kernel<<<dim3(B_ * N_), dim3(256), 0, stream>>>(
        hT, sTsrc, sTdst, cnt, nidx, out);
}

// Round 7
// 147.748 us; speedup vs baseline: 2.6073x; 1.0185x over previous
//
#include <hip/hip_runtime.h>

#define H_ 8
#define B_ 2
#define N_ 2048
#define F_ 256
#define O_ 64
#define CAP 256
#define KPAD 264   // 264 u16 row stride = 528 B; 16B-aligned, 2-way bank alias (free)

typedef unsigned short u16;
typedef unsigned int   u32;
typedef __attribute__((ext_vector_type(8))) short bf16x8;
typedef __attribute__((ext_vector_type(4))) float f32x4;

__device__ __forceinline__ float us2f(u16 u) {
    union { u32 i; float f; } c; c.i = ((u32)u) << 16; return c.f;
}
__device__ __forceinline__ u16 f2us_rn(float f) {   // round-to-nearest-even bf16
    union { float f; u32 i; } c; c.f = f;
    u32 r = c.i + 0x7FFFu + ((c.i >> 16) & 1u);
    return (u16)(r >> 16);
}

// ---------------------------------------------------------------------------
// K0: detect input dtype from adj bit patterns (bf16 vs fp32).
// fp32 0/1 adjacency words: only 0x00000000 / 0x3F800000.
// bf16 pairs also produce 0x00003F80 ([1,0]) / 0x3F803F80 ([1,1]).
// ---------------------------------------------------------------------------
__global__ void detect_kernel(const uint4* __restrict__ adj_v, int* __restrict__ flag) {
    __shared__ int found;
    if (threadIdx.x == 0) found = 0;
    __syncthreads();
#pragma unroll
    for (int i = 0; i < 16; ++i) {
        uint4 v = adj_v[threadIdx.x * 16 + i];
        u32 w[4] = {v.x, v.y, v.z, v.w};
        for (int q = 0; q < 4; ++q)
            if (w[q] == 0x00003F80u || w[q] == 0x3F803F80u) found = 1;
    }
    __syncthreads();
    if (threadIdx.x == 0) flag[0] = found;   // 1 = bf16 inputs, 0 = fp32
}

// ---------------------------------------------------------------------------
// K0b: transpose W once: Wt[h][o][f] (bf16) from W[h][f][o]. 8 blocks.
// ---------------------------------------------------------------------------
__global__ void wt_kernel(const void* __restrict__ W,
                          const int* __restrict__ flag,
                          u16* __restrict__ Wt) {
    int h  = blockIdx.x;
    int o  = threadIdx.x & 63;
    int fq = threadIdx.x >> 6;          // 0..3
    u16* dst = Wt + (size_t)h * O_ * F_ + (size_t)o * F_;
    if (flag[0]) {
        const u16* wg = (const u16*)W + (size_t)h * F_ * O_;
        for (int i = 0; i < 64; ++i) {
            int f = fq * 64 + i;
            dst[f] = wg[(size_t)f * O_ + o];
        }
    } else {
        const float* wg = (const float*)W + (size_t)h * F_ * O_;
        for (int i = 0; i < 64; ++i) {
            int f = fq * 64 + i;
            dst[f] = f2us_rn(wg[(size_t)f * O_ + o]);
        }
    }
}

// ---------------------------------------------------------------------------
// K1: MFMA projection + fused attention-vector dots.
// Block = 64 bn-rows x 1 head. A-frags direct from global x; W^T tile (from
// pre-transposed Wt) staged in LDS. 4 waves x 32 MFMA (16x16x32 bf16).
//   hT[bn][h][o] (fp32), sTsrc/sTdst[bn][h]
// ---------------------------------------------------------------------------
__global__ __launch_bounds__(256) void proj_kernel(const void* __restrict__ x,
                                                   const u16* __restrict__ Wt,
                                                   const void* __restrict__ a_src,
                                                   const void* __restrict__ a_dst,
                                                   const int* __restrict__ flag,
                                                   float* __restrict__ hT,
                                                   float* __restrict__ sTsrc,
                                                   float* __restrict__ sTdst) {
    __shared__ alignas(16) u16 wt[64 * KPAD];

    int bf   = flag[0];
    int bx   = blockIdx.x;
    int h    = bx & 7;
    int bn0  = (bx >> 3) * 64;
    int tid  = threadIdx.x;
    int wave = tid >> 6;
    int lane = tid & 63;

    // stage W^T tile: 64 rows x 256 f, uint4 copies (8 per thread)
    {
        int o    = tid >> 2;            // 0..63
        int part = tid & 3;             // 0..3
        const u16* src = Wt + (size_t)h * O_ * F_ + (size_t)o * F_ + part * 64;
        u16* dst = wt + o * KPAD + part * 64;
#pragma unroll
        for (int i = 0; i < 8; ++i)
            *(uint4*)(dst + i * 8) = *(const uint4*)(src + i * 8);
    }
    __syncthreads();

    int m_l  = lane & 15;
    int quad = lane >> 4;
    int mrow = bn0 + wave * 16 + m_l;

    f32x4 acc[4] = {{0,0,0,0},{0,0,0,0},{0,0,0,0},{0,0,0,0}};
#pragma unroll
    for (int ks = 0; ks < 8; ++ks) {
        int kofs = ks * 32 + quad * 8;
        bf16x8 afrag;
        if (bf) {
            afrag = *(const bf16x8*)((const u16*)x + (size_t)mrow * F_ + kofs);
        } else {
            const float* xr = (const float*)x + (size_t)mrow * F_ + kofs;
#pragma unroll
            for (int q = 0; q < 8; ++q) afrag[q] = (short)f2us_rn(xr[q]);
        }
#pragma unroll
        for (int nt = 0; nt < 4; ++nt) {
            bf16x8 bfrag = *(const bf16x8*)(wt + (nt * 16 + m_l) * KPAD + kofs);
            acc[nt] = __builtin_amdgcn_mfma_f32_16x16x32_bf16(afrag, bfrag, acc[nt], 0, 0, 0);
        }
    }

    // epilogue: store hT + fused a_src/a_dst row dots
    float asv[4], adv[4];
#pragma unroll
    for (int nt = 0; nt < 4; ++nt) {
        int o = nt * 16 + m_l;
        if (bf) {
            asv[nt] = us2f(((const u16*)a_src)[h * 64 + o]);
            adv[nt] = us2f(((const u16*)a_dst)[h * 64 + o]);
        } else {
            asv[nt] = ((const float*)a_src)[h * 64 + o];
            adv[nt] = ((const float*)a_dst)[h * 64 + o];
        }
    }
    float vs[4] = {0,0,0,0}, vd[4] = {0,0,0,0};
#pragma unroll
    for (int nt = 0; nt < 4; ++nt)
#pragma unroll
        for (int r = 0; r < 4; ++r) {
            float hv = acc[nt][r];
            int row = wave * 16 + quad * 4 + r;   // C/D: row = quad*4+reg, col = lane&15
            hT[(size_t)(bn0 + row) * (H_ * O_) + h * O_ + nt * 16 + m_l] = hv;
            vs[r] = fmaf(hv, asv[nt], vs[r]);
            vd[r] = fmaf(hv, adv[nt], vd[r]);
        }
#pragma unroll
    for (int r = 0; r < 4; ++r)
#pragma unroll
        for (int off = 1; off < 16; off <<= 1) {
            vs[r] += __shfl_xor(vs[r], off);
            vd[r] += __shfl_xor(vd[r], off);
        }
    if (m_l == 0) {
#pragma unroll
        for (int r = 0; r < 4; ++r) {
            int row = wave * 16 + quad * 4 + r;
            sTsrc[(size_t)(bn0 + row) * H_ + h] = vs[r];
            sTdst[(size_t)(bn0 + row) * H_ + h] = vd[r];
        }
    }
}

// ---------------------------------------------------------------------------
// K2: one block per (b,i), ALL 8 heads. Inline CSR + softmax + aggregation.
// Phase 0: build neighbor list from adj row (uint4 loads + LDS atomics).
// Phase 3: x4-unrolled float4 gathers of hT rows for MLP.
// ---------------------------------------------------------------------------
__global__ void GATLayer_88072599371930_kernel(const float* __restrict__ hT,
                                               const float* __restrict__ sTsrc,
                                               const float* __restrict__ sTdst,
                                               const void* __restrict__ adj,
                                               const int* __restrict__ flag,
                                               float* __restrict__ out) {
    __shared__ int   scnt;
    __shared__ u16   sj[CAP];
    __shared__ float se[CAP * H_];     // [k][h]
    __shared__ float mh[H_];
    __shared__ float rzh[H_];
    __shared__ float sdl[H_];
    __shared__ float sred[128 * 4];

    int bi   = blockIdx.x;
    int tid  = threadIdx.x;
    int base = bi & ~(N_ - 1);

    if (tid == 0) scnt = 0;
    if (tid < 8) sdl[tid] = sTdst[(size_t)bi * H_ + tid];
    __syncthreads();

    // Phase 0: neighbor list
    if (flag[0]) {
        const u16* arow = (const u16*)adj + (size_t)bi * N_;
        uint4 v = *(const uint4*)(arow + tid * 8);
        u32 w[4] = {v.x, v.y, v.z, v.w};
        int j0 = tid * 8;
#pragma unroll
        for (int q = 0; q < 4; ++q) {
            if (w[q] & 0xFFFFu) { int p = atomicAdd(&scnt, 1); if (p < CAP) sj[p] = (u16)(j0 + 2 * q); }
            if (w[q] >> 16)     { int p = atomicAdd(&scnt, 1); if (p < CAP) sj[p] = (u16)(j0 + 2 * q + 1); }
        }
    } else {
        const float* arow = (const float*)adj + (size_t)bi * N_;
        for (int j = tid; j < N_; j += 256) {
            if (arow[j] > 0.f) { int p = atomicAdd(&scnt, 1); if (p < CAP) sj[p] = (u16)j; }
        }
    }
    __syncthreads();
    int n = scnt < CAP ? scnt : CAP;

    if (n <= 0) {
        out[(size_t)bi * 512 + tid] = 999.0f;
        out[(size_t)bi * 512 + 256 + tid] = 999.0f;
        return;
    }

    // Phase 1: raw leaky-relu scores, [k][h] layout
    int tot = n * H_;
    for (int idx = tid; idx < tot; idx += 256) {
        int k  = idx >> 3;
        int hh = idx & 7;
        int j  = sj[k];
        float v = sdl[hh] + sTsrc[(size_t)(base + j) * H_ + hh];
        v = v > 0.f ? v : 0.2f * v;
        se[idx] = v;
    }
    __syncthreads();

    // Phase 2a: per-head max (wave 0)
    if (tid < 64) {
        int hh = tid >> 3, kk = tid & 7;
        float lm = -3.4e38f;
        for (int k = kk; k < n; k += 8) lm = fmaxf(lm, se[k * 8 + hh]);
#pragma unroll
        for (int mm = 1; mm < 8; mm <<= 1) lm = fmaxf(lm, __shfl_xor(lm, mm));
        if (kk == 0) mh[hh] = lm;
    }
    __syncthreads();

    // Phase 2b: exp
    for (int idx = tid; idx < tot; idx += 256) {
        int hh = idx & 7;
        se[idx] = __expf(se[idx] - mh[hh]);
    }
    __syncthreads();

    // Phase 2c: per-head sum -> 1/Z (wave 0)
    if (tid < 64) {
        int hh = tid >> 3, kk = tid & 7;
        float ls = 0.f;
        for (int k = kk; k < n; k += 8) ls += se[k * 8 + hh];
#pragma unroll
        for (int mm = 1; mm < 8; mm <<= 1) ls += __shfl_xor(ls, mm);
        if (kk == 0) rzh[hh] = 1.f / ls;
    }
    __syncthreads();

    // Phase 3: aggregation, x4 unrolled (4 independent gathers in flight)
    int slot = tid >> 7;
    int hh   = (tid >> 4) & 7;
    int oq   = tid & 15;
    const float* hb = hT + (size_t)base * 512 + hh * 64 + oq * 4;
    float a0 = 0.f, a1 = 0.f, a2 = 0.f, a3 = 0.f;
    int k = slot;
    for (; k + 6 < n; k += 8) {
        int   j0 = sj[k],     j1 = sj[k + 2], j2 = sj[k + 4], j3 = sj[k + 6];
        float w0 = se[k * 8 + hh],       w1 = se[(k + 2) * 8 + hh];
        float w2 = se[(k + 4) * 8 + hh], w3 = se[(k + 6) * 8 + hh];
        float4 v0 = *(const float4*)(hb + (size_t)j0 * 512);
        float4 v1 = *(const float4*)(hb + (size_t)j1 * 512);
        float4 v2 = *(const float4*)(hb + (size_t)j2 * 512);
        float4 v3 = *(const float4*)(hb + (size_t)j3 * 512);
        a0 = fmaf(w0, v0.x, a0); a1 = fmaf(w0, v0.y, a1); a2 = fmaf(w0, v0.z, a2); a3 = fmaf(w0, v0.w, a3);
        a0 = fmaf(w1, v1.x, a0); a1 = fmaf(w1, v1.y, a1); a2 = fmaf(w1, v1.z, a2); a3 = fmaf(w1, v1.w, a3);
        a0 = fmaf(w2, v2.x, a0); a1 = fmaf(w2, v2.y, a1); a2 = fmaf(w2, v2.z, a2); a3 = fmaf(w2, v2.w, a3);
        a0 = fmaf(w3, v3.x, a0); a1 = fmaf(w3, v3.y, a1); a2 = fmaf(w3, v3.z, a2); a3 = fmaf(w3, v3.w, a3);
    }
    for (; k < n; k += 2) {
        int   j = sj[k];
        float w = se[k * 8 + hh];
        float4 v = *(const float4*)(hb + (size_t)j * 512);
        a0 = fmaf(w, v.x, a0); a1 = fmaf(w, v.y, a1); a2 = fmaf(w, v.z, a2); a3 = fmaf(w, v.w, a3);
    }
    if (slot == 1) {
        float4 t; t.x = a0; t.y = a1; t.z = a2; t.w = a3;
        ((float4*)sred)[tid - 128] = t;
    }
    __syncthreads();
    if (slot == 0) {
        float4 p = ((float4*)sred)[tid];
        float rz = rzh[hh];
        float4 r;
        r.x = fmaxf((a0 + p.x) * rz, 0.f);
        r.y = fmaxf((a1 + p.y) * rz, 0.f);
        r.z = fmaxf((a2 + p.z) * rz, 0.f);
        r.w = fmaxf((a3 + p.w) * rz, 0.f);
        *(float4*)(out + (size_t)bi * 512 + tid * 4) = r;
    }
}

// ---------------------------------------------------------------------------
extern "C" void kernel_launch(void* const* d_in, const int* in_sizes, int n_in,
                              void* d_out, int out_size, void* d_ws, size_t ws_size,
                              hipStream_t stream) {
    const void *x = 0, *adj = 0, *W = 0, *a_src = 0, *a_dst = 0;
    for (int i = 0; i < n_in; ++i) {
        long sz = in_sizes[i];
        if (sz == (long)B_ * N_ * F_)      x = d_in[i];
        else if (sz == (long)B_ * N_ * N_) adj = d_in[i];
        else if (sz == (long)H_ * F_ * O_) W = d_in[i];
        else if (sz == (long)H_ * O_) { if (!a_src) a_src = d_in[i]; else a_dst = d_in[i]; }
    }
    if (!x)     x     = d_in[0];
    if (!adj)   adj   = d_in[1];
    if (!W)     W     = d_in[2];
    if (!a_src) a_src = d_in[3];
    if (!a_dst) a_dst = d_in[4];

    float* out = (float*)d_out;

    char* ws = (char*)d_ws;
    size_t off = 0;
    int*   flag  = (int*)(ws + off);   off += 256;
    float* hT    = (float*)(ws + off); off += (size_t)B_ * N_ * H_ * O_ * 4;  // 8 MB
    float* sTsrc = (float*)(ws + off); off += (size_t)B_ * N_ * H_ * 4;       // 128 KB
    float* sTdst = (float*)(ws + off); off += (size_t)B_ * N_ * H_ * 4;       // 128 KB
    u16*   Wt    = (u16*)(ws + off);   off += (size_t)H_ * O_ * F_ * 2;       // 256 KB

    detect_kernel<<<dim3(1), dim3(256), 0, stream>>>((const uint4*)adj, flag);
    wt_kernel<<<dim3(H_), dim3(256), 0, stream>>>(W, flag, Wt);
    proj_kernel<<<dim3((N_ * B_ / 64) * H_), dim3(256), 0, stream>>>(
        x, Wt, a_src, a_dst, flag, hT, sTsrc, sTdst);
    GATLayer_88072599371930_kernel<<<dim3(B_ * N_), dim3(256), 0, stream>>>(
        hT, sTsrc, sTdst, adj, flag, out);
}

// Round 8
// 128.485 us; speedup vs baseline: 2.9982x; 1.1499x over previous
//
#include <hip/hip_runtime.h>

#define H_ 8
#define B_ 2
#define N_ 2048
#define F_ 256
#define O_ 64
#define CAP 256

typedef unsigned short u16;
typedef unsigned int   u32;
typedef __attribute__((ext_vector_type(8))) short bf16x8;
typedef __attribute__((ext_vector_type(4))) float f32x4;

__device__ __forceinline__ float us2f(u16 u) {
    union { u32 i; float f; } c; c.i = ((u32)u) << 16; return c.f;
}
__device__ __forceinline__ float hi2f(u32 w) {          // high 16 bits as bf16
    union { u32 i; float f; } c; c.i = w & 0xFFFF0000u; return c.f;
}
__device__ __forceinline__ float lo2f(u32 w) {          // low 16 bits as bf16
    union { u32 i; float f; } c; c.i = w << 16; return c.f;
}
__device__ __forceinline__ u16 f2us_rn(float f) {       // round-nearest-even bf16
    union { float f; u32 i; } c; c.f = f;
    u32 r = c.i + 0x7FFFu + ((c.i >> 16) & 1u);
    return (u16)(r >> 16);
}
// dtype flag from adj word 0: adj[0][0]=1.0 (self-loop). bf16 -> low16==0x3F80.
__device__ __forceinline__ int detect_bf(const void* adj) {
    u32 w0 = *(const u32*)adj;
    return (w0 & 0xFFFFu) == 0x3F80u;
}

// ---------------------------------------------------------------------------
// K0: transpose W once: Wt[h][o][f] (bf16) from W[h][f][o].
// 64 blocks; thread packs 8 strided L2-hot reads -> one uint4 coalesced write.
// ---------------------------------------------------------------------------
__global__ __launch_bounds__(256) void wt_kernel(const void* __restrict__ W,
                                                 const void* __restrict__ adj,
                                                 u16* __restrict__ Wt) {
    int bf = detect_bf(adj);
    int g  = blockIdx.x * 256 + threadIdx.x;   // 0 .. 16383
    int h  = g >> 11;
    int o  = (g >> 5) & 63;
    int fc = g & 31;                            // f-chunk of 8
    u16 tmp[8];
    if (bf) {
        const u16* wg = (const u16*)W + (size_t)h * F_ * O_ + o;
#pragma unroll
        for (int q = 0; q < 8; ++q) tmp[q] = wg[(size_t)(fc * 8 + q) * O_];
    } else {
        const float* wg = (const float*)W + (size_t)h * F_ * O_ + o;
#pragma unroll
        for (int q = 0; q < 8; ++q) tmp[q] = f2us_rn(wg[(size_t)(fc * 8 + q) * O_]);
    }
    *(uint4*)(Wt + (size_t)h * O_ * F_ + (size_t)o * F_ + fc * 8) = *(uint4*)tmp;
}

// ---------------------------------------------------------------------------
// K1: MFMA projection + fused attention-vector dots. NO LDS.
// Block = 64 bn-rows x 1 head; A-frags direct from x, B-frags direct from Wt
// (both L2-resident). 4 waves x 32 MFMA (16x16x32 bf16).
//   hTb[bn][h][o] (bf16), sTsrc/sTdst[bn][h] (fp32)
// ---------------------------------------------------------------------------
__global__ __launch_bounds__(256) void proj_kernel(const void* __restrict__ x,
                                                   const u16* __restrict__ Wt,
                                                   const void* __restrict__ a_src,
                                                   const void* __restrict__ a_dst,
                                                   const void* __restrict__ adj,
                                                   u16* __restrict__ hTb,
                                                   float* __restrict__ sTsrc,
                                                   float* __restrict__ sTdst) {
    int bf   = detect_bf(adj);
    int bx   = blockIdx.x;
    int h    = bx & 7;
    int bn0  = (bx >> 3) * 64;
    int tid  = threadIdx.x;
    int wave = tid >> 6;
    int lane = tid & 63;
    int m_l  = lane & 15;
    int quad = lane >> 4;
    int mrow = bn0 + wave * 16 + m_l;

    const u16* wtb = Wt + (size_t)h * O_ * F_;

    f32x4 acc[4] = {{0,0,0,0},{0,0,0,0},{0,0,0,0},{0,0,0,0}};
#pragma unroll
    for (int ks = 0; ks < 8; ++ks) {
        int kofs = ks * 32 + quad * 8;
        bf16x8 afrag;
        if (bf) {
            afrag = *(const bf16x8*)((const u16*)x + (size_t)mrow * F_ + kofs);
        } else {
            const float* xr = (const float*)x + (size_t)mrow * F_ + kofs;
#pragma unroll
            for (int q = 0; q < 8; ++q) afrag[q] = (short)f2us_rn(xr[q]);
        }
#pragma unroll
        for (int nt = 0; nt < 4; ++nt) {
            bf16x8 bfrag = *(const bf16x8*)(wtb + (size_t)(nt * 16 + m_l) * F_ + kofs);
            acc[nt] = __builtin_amdgcn_mfma_f32_16x16x32_bf16(afrag, bfrag, acc[nt], 0, 0, 0);
        }
    }

    // epilogue: bf16 hT stores + fused a_src/a_dst row dots
    float asv[4], adv[4];
#pragma unroll
    for (int nt = 0; nt < 4; ++nt) {
        int o = nt * 16 + m_l;
        if (bf) {
            asv[nt] = us2f(((const u16*)a_src)[h * 64 + o]);
            adv[nt] = us2f(((const u16*)a_dst)[h * 64 + o]);
        } else {
            asv[nt] = ((const float*)a_src)[h * 64 + o];
            adv[nt] = ((const float*)a_dst)[h * 64 + o];
        }
    }
    float vs[4] = {0,0,0,0}, vd[4] = {0,0,0,0};
#pragma unroll
    for (int nt = 0; nt < 4; ++nt)
#pragma unroll
        for (int r = 0; r < 4; ++r) {
            float hv = acc[nt][r];
            int row = wave * 16 + quad * 4 + r;   // C/D: row = quad*4+reg, col = lane&15
            hTb[(size_t)(bn0 + row) * 512 + h * 64 + nt * 16 + m_l] = f2us_rn(hv);
            vs[r] = fmaf(hv, asv[nt], vs[r]);
            vd[r] = fmaf(hv, adv[nt], vd[r]);
        }
#pragma unroll
    for (int r = 0; r < 4; ++r)
#pragma unroll
        for (int off = 1; off < 16; off <<= 1) {
            vs[r] += __shfl_xor(vs[r], off);
            vd[r] += __shfl_xor(vd[r], off);
        }
    if (m_l == 0) {
#pragma unroll
        for (int r = 0; r < 4; ++r) {
            int row = wave * 16 + quad * 4 + r;
            sTsrc[(size_t)(bn0 + row) * H_ + h] = vs[r];
            sTdst[(size_t)(bn0 + row) * H_ + h] = vd[r];
        }
    }
}

// ---------------------------------------------------------------------------
// K2: one block per (b,i), ALL 8 heads. Inline CSR + softmax + aggregation.
// Phase 3: wave = one whole 1KB bf16 hT row per k (lane = (hh,oq8), 16B/lane,
// fully coalesced); k += 4 across waves, x2 unrolled; LDS cross-wave reduce.
// ---------------------------------------------------------------------------
__global__ __launch_bounds__(256) void GATLayer_88072599371930_kernel(
        const u16* __restrict__ hTb,
        const float* __restrict__ sTsrc,
        const float* __restrict__ sTdst,
        const void* __restrict__ adj,
        float* __restrict__ out) {
    __shared__ int   scnt;
    __shared__ u16   sj[CAP];
    __shared__ float se[CAP * H_];      // [k][h], 8 KB
    __shared__ float mh[H_];
    __shared__ float rzh[H_];
    __shared__ float sdl[H_];
    __shared__ float sred[8 * 192];     // [e][wv-1,lane], 6 KB, conflict-free

    int bi   = blockIdx.x;
    int tid  = threadIdx.x;
    int base = bi & ~(N_ - 1);
    int bf   = detect_bf(adj);

    if (tid == 0) scnt = 0;
    if (tid < 8) sdl[tid] = sTdst[(size_t)bi * H_ + tid];
    __syncthreads();

    // Phase 0: neighbor list from own adj row
    if (bf) {
        const u16* arow = (const u16*)adj + (size_t)bi * N_;
        uint4 v = *(const uint4*)(arow + tid * 8);
        u32 w[4] = {v.x, v.y, v.z, v.w};
        int j0 = tid * 8;
#pragma unroll
        for (int q = 0; q < 4; ++q) {
            if (w[q] & 0xFFFFu) { int p = atomicAdd(&scnt, 1); if (p < CAP) sj[p] = (u16)(j0 + 2 * q); }
            if (w[q] >> 16)     { int p = atomicAdd(&scnt, 1); if (p < CAP) sj[p] = (u16)(j0 + 2 * q + 1); }
        }
    } else {
        const float* arow = (const float*)adj + (size_t)bi * N_;
        for (int j = tid; j < N_; j += 256) {
            if (arow[j] > 0.f) { int p = atomicAdd(&scnt, 1); if (p < CAP) sj[p] = (u16)j; }
        }
    }
    __syncthreads();
    int n = scnt < CAP ? scnt : CAP;

    if (n <= 0) {
        out[(size_t)bi * 512 + tid] = 999.0f;
        out[(size_t)bi * 512 + 256 + tid] = 999.0f;
        return;
    }

    // Phase 1: raw leaky-relu scores, [k][h]
    int tot = n * H_;
    for (int idx = tid; idx < tot; idx += 256) {
        int k  = idx >> 3;
        int hh = idx & 7;
        int j  = sj[k];
        float v = sdl[hh] + sTsrc[(size_t)(base + j) * H_ + hh];
        v = v > 0.f ? v : 0.2f * v;
        se[idx] = v;
    }
    __syncthreads();

    // Phase 2a: per-head max (wave 0)
    if (tid < 64) {
        int hh = tid >> 3, kk = tid & 7;
        float lm = -3.4e38f;
        for (int k = kk; k < n; k += 8) lm = fmaxf(lm, se[k * 8 + hh]);
#pragma unroll
        for (int mm = 1; mm < 8; mm <<= 1) lm = fmaxf(lm, __shfl_xor(lm, mm));
        if (kk == 0) mh[hh] = lm;
    }
    __syncthreads();
    // Phase 2b: exp
    for (int idx = tid; idx < tot; idx += 256) {
        int hh = idx & 7;
        se[idx] = __expf(se[idx] - mh[hh]);
    }
    __syncthreads();
    // Phase 2c: per-head sum -> 1/Z (wave 0)
    if (tid < 64) {
        int hh = tid >> 3, kk = tid & 7;
        float ls = 0.f;
        for (int k = kk; k < n; k += 8) ls += se[k * 8 + hh];
#pragma unroll
        for (int mm = 1; mm < 8; mm <<= 1) ls += __shfl_xor(ls, mm);
        if (kk == 0) rzh[hh] = 1.f / ls;
    }
    __syncthreads();

    // Phase 3: wave wv handles k = wv, wv+4, ... ; lane = (hh, oq8)
    int wv   = tid >> 6;
    int lane = tid & 63;
    int hh   = lane >> 3;
    int oq8  = lane & 7;
    const u16* hb = hTb + (size_t)base * 512 + hh * 64 + oq8 * 8;

    float a0 = 0.f, a1 = 0.f, a2 = 0.f, a3 = 0.f;
    float a4 = 0.f, a5 = 0.f, a6 = 0.f, a7 = 0.f;
    int k = wv;
    for (; k + 4 < n; k += 8) {
        int   j0 = sj[k], j1 = sj[k + 4];
        float w0 = se[k * 8 + hh], w1 = se[(k + 4) * 8 + hh];
        uint4 v0 = *(const uint4*)(hb + (size_t)j0 * 512);
        uint4 v1 = *(const uint4*)(hb + (size_t)j1 * 512);
        a0 = fmaf(w0, lo2f(v0.x), a0); a1 = fmaf(w0, hi2f(v0.x), a1);
        a2 = fmaf(w0, lo2f(v0.y), a2); a3 = fmaf(w0, hi2f(v0.y), a3);
        a4 = fmaf(w0, lo2f(v0.z), a4); a5 = fmaf(w0, hi2f(v0.z), a5);
        a6 = fmaf(w0, lo2f(v0.w), a6); a7 = fmaf(w0, hi2f(v0.w), a7);
        a0 = fmaf(w1, lo2f(v1.x), a0); a1 = fmaf(w1, hi2f(v1.x), a1);
        a2 = fmaf(w1, lo2f(v1.y), a2); a3 = fmaf(w1, hi2f(v1.y), a3);
        a4 = fmaf(w1, lo2f(v1.z), a4); a5 = fmaf(w1, hi2f(v1.z), a5);
        a6 = fmaf(w1, lo2f(v1.w), a6); a7 = fmaf(w1, hi2f(v1.w), a7);
    }
    for (; k < n; k += 4) {
        int   j = sj[k];
        float w = se[k * 8 + hh];
        uint4 v = *(const uint4*)(hb + (size_t)j * 512);
        a0 = fmaf(w, lo2f(v.x), a0); a1 = fmaf(w, hi2f(v.x), a1);
        a2 = fmaf(w, lo2f(v.y), a2); a3 = fmaf(w, hi2f(v.y), a3);
        a4 = fmaf(w, lo2f(v.z), a4); a5 = fmaf(w, hi2f(v.z), a5);
        a6 = fmaf(w, lo2f(v.w), a6); a7 = fmaf(w, hi2f(v.w), a7);
    }

    if (wv) {
        int p = (wv - 1) * 64 + lane;
        sred[0 * 192 + p] = a0; sred[1 * 192 + p] = a1;
        sred[2 * 192 + p] = a2; sred[3 * 192 + p] = a3;
        sred[4 * 192 + p] = a4; sred[5 * 192 + p] = a5;
        sred[6 * 192 + p] = a6; sred[7 * 192 + p] = a7;
    }
    __syncthreads();
    if (wv == 0) {
        float r[8] = {a0, a1, a2, a3, a4, a5, a6, a7};
        float rz = rzh[hh];
#pragma unroll
        for (int e = 0; e < 8; ++e) {
            float t = r[e] + sred[e * 192 + lane] + sred[e * 192 + 64 + lane]
                           + sred[e * 192 + 128 + lane];
            r[e] = fmaxf(t * rz, 0.f);
        }
        float4 o0; o0.x = r[0]; o0.y = r[1]; o0.z = r[2]; o0.w = r[3];
        float4 o1; o1.x = r[4]; o1.y = r[5]; o1.z = r[6]; o1.w = r[7];
        float* op = out + (size_t)bi * 512 + hh * 64 + oq8 * 8;
        *(float4*)op = o0;
        *(float4*)(op + 4) = o1;
    }
}

// ---------------------------------------------------------------------------
extern "C" void kernel_launch(void* const* d_in, const int* in_sizes, int n_in,
                              void* d_out, int out_size, void* d_ws, size_t ws_size,
                              hipStream_t stream) {
    const void *x = 0, *adj = 0, *W = 0, *a_src = 0, *a_dst = 0;
    for (int i = 0; i < n_in; ++i) {
        long sz = in_sizes[i];
        if (sz == (long)B_ * N_ * F_)      x = d_in[i];
        else if (sz == (long)B_ * N_ * N_) adj = d_in[i];
        else if (sz == (long)H_ * F_ * O_) W = d_in[i];
        else if (sz == (long)H_ * O_) { if (!a_src) a_src = d_in[i]; else a_dst = d_in[i]; }
    }
    if (!x)     x     = d_in[0];
    if (!adj)   adj   = d_in[1];
    if (!W)     W     = d_in[2];
    if (!a_src) a_src = d_in[3];
    if (!a_dst) a_dst = d_in[4];

    float* out = (float*)d_out;

    char* ws = (char*)d_ws;
    size_t off = 0;
    u16*   hTb   = (u16*)(ws + off);   off += (size_t)B_ * N_ * H_ * O_ * 2;  // 4 MB
    float* sTsrc = (float*)(ws + off); off += (size_t)B_ * N_ * H_ * 4;       // 128 KB
    float* sTdst = (float*)(ws + off); off += (size_t)B_ * N_ * H_ * 4;       // 128 KB
    u16*   Wt    = (u16*)(ws + off);   off += (size_t)H_ * O_ * F_ * 2;       // 256 KB

    wt_kernel<<<dim3(64), dim3(256), 0, stream>>>(W, adj, Wt);
    proj_kernel<<<dim3((N_ * B_ / 64) * H_), dim3(256), 0, stream>>>(
        x, Wt, a_src, a_dst, adj, hTb, sTsrc, sTdst);
    GATLayer_88072599371930_kernel<<<dim3(B_ * N_), dim3(256), 0, stream>>>(
        hTb, sTsrc, sTdst, adj, out);
}